// Round 5
// baseline (317.406 us; speedup 1.0000x reference)
//
#include <hip/hip_runtime.h>
#include <hip/hip_bf16.h>

typedef unsigned short u16;
typedef __attribute__((ext_vector_type(4))) float f32x4;
typedef __attribute__((ext_vector_type(8))) short s16x8;

constexpr int DMODEL = 1024;
constexpr int NH     = 16;
constexpr int DK     = 64;
constexpr int SEQ    = 4096;
constexpr int BATCH  = 2;
constexpr int BS     = BATCH * SEQ;     // 8192
constexpr int NX     = BS * DMODEL;     // 8,388,608
constexpr int NW     = DMODEL * DMODEL; // 1,048,576

__device__ __forceinline__ u16 f2bf(float f) {
  union { float f; unsigned u; } v; v.f = f;
  unsigned r = v.u + 0x7fffu + ((v.u >> 16) & 1u);
  return (u16)(r >> 16);
}
__device__ __forceinline__ float bf2f(u16 h) {
  union { unsigned u; float f; } v; v.u = ((unsigned)h) << 16;
  return v.f;
}
// packed f32x2 -> bf16x2 via v_cvt_pk_bf16_f32 (compiler emits from this API)
__device__ __forceinline__ unsigned pk2(float a, float b) {
  float2 t; t.x = a; t.y = b;
  __hip_bfloat162 h = __float22bfloat162_rn(t);
  return *reinterpret_cast<unsigned*>(&h);
}
__device__ __forceinline__ void gload_lds16(const void* g, void* l) {
  __builtin_amdgcn_global_load_lds(
      (const __attribute__((address_space(1))) void*)g,
      (__attribute__((address_space(3))) void*)l, 16, 0, 0);
}

// ---------------- fp32 -> bf16 conversion for x and W[qkvo] ----------------
__global__ __launch_bounds__(256) void convert_all(
    const float* __restrict__ x, const float* __restrict__ wq,
    const float* __restrict__ wk, const float* __restrict__ wv,
    const float* __restrict__ wo, u16* __restrict__ xb, u16* __restrict__ Wb) {
  int t = blockIdx.x * 256 + threadIdx.x;
  int i = t * 4;
  const float* src; u16* dst;
  if (i < NX) { src = x + i; dst = xb + i; }
  else {
    int j = i - NX; int w = j >> 20; int jj = j & (NW - 1);
    src = (w == 0 ? wq : w == 1 ? wk : w == 2 ? wv : wo) + jj;
    dst = Wb + j;
  }
  float4 v = *reinterpret_cast<const float4*>(src);
  uint2 pk; pk.x = pk2(v.x, v.y); pk.y = pk2(v.z, v.w);
  *reinterpret_cast<uint2*>(dst) = pk;
}

// ---------------- 128x128 bf16 GEMM, C = A * B^T (B rows = output cols) ----
template <int EPI>
__global__ __launch_bounds__(256) void gemm128(
    const u16* __restrict__ A, const u16* __restrict__ B,
    u16* __restrict__ Qw, u16* __restrict__ Kw, u16* __restrict__ Vt,
    float* __restrict__ Co) {
  __shared__ u16 lA[128 * 32];
  __shared__ u16 lB[128 * 32];
  const int tid = threadIdx.x, w = tid >> 6, l = tid & 63;
  const int wr = w >> 1, wc = w & 1;
  const int m0 = blockIdx.y * 128, n0 = blockIdx.x * 128;
  constexpr int K = 1024;
  f32x4 acc[4][4] = {};
  const int li = l & 15, lg = l >> 4;
  const int srow = l >> 2, skc = (l & 3) * 8;
  for (int k0 = 0; k0 < K; k0 += 32) {
    __syncthreads();
#pragma unroll
    for (int cc = 0; cc < 2; ++cc) {
      const int c = 2 * w + cc;
      const int row = c * 16 + srow;
      gload_lds16(A + (size_t)(m0 + row) * K + k0 + skc, &lA[c * 512]);
      gload_lds16(B + (size_t)(n0 + row) * K + k0 + skc, &lB[c * 512]);
    }
    __syncthreads();
    s16x8 af[4], bfr[4];
#pragma unroll
    for (int i = 0; i < 4; ++i)
      af[i] = *reinterpret_cast<const s16x8*>(&lA[(wr * 64 + i * 16 + li) * 32 + lg * 8]);
#pragma unroll
    for (int j = 0; j < 4; ++j)
      bfr[j] = *reinterpret_cast<const s16x8*>(&lB[(wc * 64 + j * 16 + li) * 32 + lg * 8]);
#pragma unroll
    for (int i = 0; i < 4; ++i)
#pragma unroll
      for (int j = 0; j < 4; ++j)
        acc[i][j] = __builtin_amdgcn_mfma_f32_16x16x32_bf16(af[i], bfr[j], acc[i][j], 0, 0, 0);
  }
#pragma unroll
  for (int i = 0; i < 4; ++i) {
    const int mbase = m0 + wr * 64 + i * 16 + lg * 4;
#pragma unroll
    for (int j = 0; j < 4; ++j) {
      const int n = n0 + wc * 64 + j * 16 + li;
      if (EPI == 0) {
        const int which = n >> 10, nn = n & 1023, h = nn >> 6, d = nn & 63;
#pragma unroll
        for (int r = 0; r < 4; ++r) {
          const int m = mbase + r, b = m >> 12, s = m & (SEQ - 1);
          const int bh = b * NH + h;
          const u16 val = f2bf(acc[i][j][r]);
          if (which == 0)      Qw[((size_t)bh * SEQ + s) * DK + d] = val;
          else if (which == 1) Kw[((size_t)bh * SEQ + s) * DK + d] = val;
          else                 Vt[((size_t)bh * DK + d) * SEQ + s] = val;
        }
      } else {
#pragma unroll
        for (int r = 0; r < 4; ++r)
          Co[(size_t)(mbase + r) * DMODEL + n] = acc[i][j][r];
      }
    }
  }
}

// -------- RoPE in-place; Q additionally scaled by (1/8)*log2(e) for exp2 ---
__global__ __launch_bounds__(256) void rope_qk(u16* __restrict__ Qw, u16* __restrict__ Kw,
                                               const int* __restrict__ pos) {
  const int TOT = BATCH * NH * SEQ * 32;  // pairs per tensor
  int t = blockIdx.x * 256 + threadIdx.x;
  const bool isQ = (t < TOT);
  u16* arr = isQ ? Qw : Kw;
  int p = isQ ? t : t - TOT;
  const int i = p & 31;
  const int s = (p >> 5) & (SEQ - 1);
  const int bh = p >> 17;
  const float inv = expf(-(float)i * 0.28782313662425574f);
  const float ang = (float)pos[s] * inv;
  float sn, cs;
  sincosf(ang, &sn, &cs);
  const float sc = isQ ? 0.18033688011112042f : 1.0f;  // 0.125 * log2(e)
  u16* ptr = arr + ((size_t)bh * SEQ + s) * DK + 2 * i;
  unsigned v = *reinterpret_cast<unsigned*>(ptr);
  float xe = bf2f((u16)(v & 0xffffu)), xo = bf2f((u16)(v >> 16));
  float oe = (xe * cs - xo * sn) * sc;
  float oo = (xe * sn + xo * cs) * sc;
  *reinterpret_cast<unsigned*>(ptr) = pk2(oe, oo);
}

// ---------------- causal flash attention, 8 waves x 16 q-rows --------------
// 512 uniform paired blocks (tiles 31-j and j, 66 k-iters), 512 threads.
// 16 waves/CU (2 blocks) for latency hiding. Swapped MFMAs keep softmax
// lane-local; scores are in log2 domain (scale folded into Q), exp2f.
__global__ __launch_bounds__(512, 4) void attn_kernel(
    const u16* __restrict__ Qw, const u16* __restrict__ Kw,
    const u16* __restrict__ Vt, u16* __restrict__ Ob) {
  __shared__ __align__(16) u16 Kb[2][4096];
  __shared__ __align__(16) u16 Vb[2][4096];
  __shared__ __align__(16) u16 Pb[8][16][68];  // stride 136B: banks 2*li, distinct
  const int tid = threadIdx.x, w = tid >> 6, l = tid & 63;
  const int li = l & 15, lg = l >> 4;
  const int id = blockIdx.x;
  const int g = (id & 7) * 64 + (id >> 3);    // XCD-chunked (64 blocks/XCD)
  const int bh = g >> 4;                      // 4 heads per XCD chunk
  const int j  = g & 15;                      // pair index
  const int tA = 31 - j, tB = j;              // heavy first
  const int nA = 2 * tA + 2, nB = 2 * tB + 2; // 66 total iterations
  const u16* Qh = Qw + (size_t)bh * SEQ * DK;
  const u16* Kh = Kw + (size_t)bh * SEQ * DK;
  const u16* Vh = Vt + (size_t)bh * DK * SEQ;
  const int b = bh >> 4, h = bh & 15;

  // staging: 512 threads x 16B = one full 64x128B tile per issue
  const int row0  = tid >> 3;                        // 0..63
  const int scol0 = ((tid & 7) * 16) ^ ((row0 & 7) << 4);

  s16x8 aq[2];
  f32x4 o[4];
  float mrun, lrun;

  auto loadQ = [&](int q0) {
#pragma unroll
    for (int ds = 0; ds < 2; ++ds)
      aq[ds] = *reinterpret_cast<const s16x8*>(
          &Qh[(size_t)(q0 + li) * DK + ds * 32 + lg * 8]);
  };
  auto resetState = [&]() {
    mrun = -1e30f; lrun = 0.f;
#pragma unroll
    for (int ds = 0; ds < 4; ++ds) o[ds] = f32x4{0.f, 0.f, 0.f, 0.f};
  };
  auto writeO = [&](int q0) {
    const float inv = 1.f / lrun;
    const int s = q0 + li;
    u16* orow = Ob + ((size_t)(b * SEQ + s)) * DMODEL + h * DK;
#pragma unroll
    for (int ds = 0; ds < 4; ++ds) {
      uint2 pkv;
      pkv.x = pk2(o[ds][0] * inv, o[ds][1] * inv);
      pkv.y = pk2(o[ds][2] * inv, o[ds][3] * inv);
      *reinterpret_cast<uint2*>(orow + ds * 16 + lg * 4) = pkv;
    }
  };
  auto stage = [&](int buf, int kt) {
    const char* ksrc = (const char*)Kh + (size_t)(kt + row0) * 128 + scol0;
    gload_lds16(ksrc, (char*)&Kb[buf][0] + (size_t)w * 1024);
    const char* vsrc = (const char*)Vh + (size_t)row0 * (SEQ * 2) + kt * 2 + scol0;
    gload_lds16(vsrc, (char*)&Vb[buf][0] + (size_t)w * 1024);
  };

  int q0 = tA * 128 + w * 16;
  loadQ(q0);
  resetState();
  stage(0, 0);
  int kt = 0;
  const int ntot = nA + nB;
  for (int it = 0; it < ntot; ++it) {
    asm volatile("s_waitcnt vmcnt(0)" ::: "memory");  // current buf staged
    __builtin_amdgcn_s_barrier();
    __builtin_amdgcn_sched_barrier(0);
    const int itn = it + 1;
    const int ktn = (itn < nA) ? 64 * itn : (itn < ntot ? 64 * (itn - nA) : 0);
    stage(itn & 1, ktn);
    if (kt < q0 + 16) {  // skip fully-masked tiles for this wave
      const int cur = it & 1;
      // ---- QK^T (swapped): sc[ks] rows k=kt+ks*16+lg*4+r, col q=q0+li
      f32x4 sc[4];
      __builtin_amdgcn_s_setprio(1);
#pragma unroll
      for (int ks = 0; ks < 4; ++ks) {
        const int R = ks * 16 + li;
        const char* kbase = (const char*)&Kb[cur][0] + R * 128;
        const int sw = (R & 7) << 4;
        s16x8 bk0 = *reinterpret_cast<const s16x8*>(kbase + ((lg * 16) ^ sw));
        s16x8 bk1 = *reinterpret_cast<const s16x8*>(kbase + (((64 + lg * 16)) ^ sw));
        f32x4 z = {0.f, 0.f, 0.f, 0.f};
        z = __builtin_amdgcn_mfma_f32_16x16x32_bf16(bk0, aq[0], z, 0, 0, 0);
        z = __builtin_amdgcn_mfma_f32_16x16x32_bf16(bk1, aq[1], z, 0, 0, 0);
        sc[ks] = z;
      }
      __builtin_amdgcn_s_setprio(0);
      if (kt + 63 > q0) {  // causal mask: k > q
#pragma unroll
        for (int ks = 0; ks < 4; ++ks)
#pragma unroll
          for (int r = 0; r < 4; ++r)
            if (kt + ks * 16 + lg * 4 + r > q0 + li) sc[ks][r] = -1e30f;
      }
      // ---- online softmax (log2 domain), lane-local per q
      float a0 = fmaxf(fmaxf(sc[0][0], sc[0][1]), fmaxf(sc[0][2], sc[0][3]));
      float a1 = fmaxf(fmaxf(sc[1][0], sc[1][1]), fmaxf(sc[1][2], sc[1][3]));
      float a2 = fmaxf(fmaxf(sc[2][0], sc[2][1]), fmaxf(sc[2][2], sc[2][3]));
      float a3 = fmaxf(fmaxf(sc[3][0], sc[3][1]), fmaxf(sc[3][2], sc[3][3]));
      float pm = fmaxf(fmaxf(a0, a1), fmaxf(a2, a3));
      pm = fmaxf(pm, __shfl_xor(pm, 16, 64));
      pm = fmaxf(pm, __shfl_xor(pm, 32, 64));
      const bool ok = (pm <= mrun + 8.f);
      if (!__all(ok)) {  // defer-max: rescale path is rare
        const float mn = fmaxf(mrun, pm);
        const float fs = exp2f(mrun - mn);
        mrun = mn; lrun *= fs;
#pragma unroll
        for (int ds = 0; ds < 4; ++ds) o[ds] *= fs;
      }
      float rs = 0.f;
#pragma unroll
      for (int ks = 0; ks < 4; ++ks)
#pragma unroll
        for (int r = 0; r < 4; ++r) {
          const float p = exp2f(sc[ks][r] - mrun);
          sc[ks][r] = p; rs += p;
        }
      rs += __shfl_xor(rs, 16, 64);
      rs += __shfl_xor(rs, 32, 64);
      lrun += rs;
      // pack P rows k=ks*16+lg*4..+3 for q-row li -> b64 writes
#pragma unroll
      for (int ks = 0; ks < 4; ++ks) {
        uint2 pw;
        pw.x = pk2(sc[ks][0], sc[ks][1]);
        pw.y = pk2(sc[ks][2], sc[ks][3]);
        *reinterpret_cast<uint2*>(&Pb[w][li][ks * 16 + lg * 4]) = pw;
      }
      // ---- PV (swapped): o[ds] rows d=ds*16+lg*4+r, col q=li
      s16x8 ap[2];
#pragma unroll
      for (int kp = 0; kp < 2; ++kp)
        ap[kp] = *reinterpret_cast<const s16x8*>(&Pb[w][li][kp * 32 + lg * 8]);
      __builtin_amdgcn_s_setprio(1);
#pragma unroll
      for (int ds = 0; ds < 4; ++ds) {
        const int R = ds * 16 + li;
        const char* vbase = (const char*)&Vb[cur][0] + R * 128;
        const int sw = (R & 7) << 4;
        s16x8 bv0 = *reinterpret_cast<const s16x8*>(vbase + ((lg * 16) ^ sw));
        s16x8 bv1 = *reinterpret_cast<const s16x8*>(vbase + (((64 + lg * 16)) ^ sw));
        o[ds] = __builtin_amdgcn_mfma_f32_16x16x32_bf16(bv0, ap[0], o[ds], 0, 0, 0);
        o[ds] = __builtin_amdgcn_mfma_f32_16x16x32_bf16(bv1, ap[1], o[ds], 0, 0, 0);
      }
      __builtin_amdgcn_s_setprio(0);
    }
    if (it == nA - 1) {  // phase switch: flush tile A, start tile B
      writeO(q0);
      q0 = tB * 128 + w * 16;
      loadQ(q0);
      resetState();
    }
    kt = ktn;
  }
  writeO(q0);
}

extern "C" void kernel_launch(void* const* d_in, const int* in_sizes, int n_in,
                              void* d_out, int out_size, void* d_ws, size_t ws_size,
                              hipStream_t stream) {
  const float* x  = (const float*)d_in[0];
  const int*  pos = (const int*)d_in[1];
  const float* wq = (const float*)d_in[2];
  const float* wk = (const float*)d_in[3];
  const float* wv = (const float*)d_in[4];
  const float* wo = (const float*)d_in[5];
  float* out = (float*)d_out;

  u16* Wb = (u16*)d_ws;               // 4*NW bf16 (Wq|Wk|Wv|Wo)
  u16* xb = Wb + 4 * (size_t)NW;      // NX bf16
  u16* Qw = xb + (size_t)NX;          // (b,h,s,d)
  u16* Kw = Qw + (size_t)NX;          // (b,h,s,d)
  u16* Vt = Kw + (size_t)NX;          // (b,h,d,s)
  u16* Ab = xb;                       // reuse x-bf16 region for attn output

  convert_all<<<(NX + 4 * NW) / 4 / 256, 256, 0, stream>>>(x, wq, wk, wv, wo, xb, Wb);
  gemm128<0><<<dim3(24, 64), 256, 0, stream>>>(xb, Wb, Qw, Kw, Vt, nullptr);
  rope_qk<<<2 * (BATCH * NH * SEQ * 32) / 256, 256, 0, stream>>>(Qw, Kw, pos);
  attn_kernel<<<512, 512, 0, stream>>>(Qw, Kw, Vt, Ab);
  gemm128<1><<<dim3(8, 64), 256, 0, stream>>>(Ab, Wb + 3 * (size_t)NW, nullptr, nullptr, nullptr, out);
}

// Round 6
// 307.630 us; speedup vs baseline: 1.0318x; 1.0318x over previous
//
#include <hip/hip_runtime.h>
#include <hip/hip_bf16.h>

typedef unsigned short u16;
typedef __attribute__((ext_vector_type(4))) float f32x4;
typedef __attribute__((ext_vector_type(16))) float f32x16;
typedef __attribute__((ext_vector_type(8))) short s16x8;
typedef __attribute__((ext_vector_type(2))) unsigned u32x2;

constexpr int DMODEL = 1024;
constexpr int NH     = 16;
constexpr int DK     = 64;
constexpr int SEQ    = 4096;
constexpr int BATCH  = 2;
constexpr int BS     = BATCH * SEQ;     // 8192
constexpr int NX     = BS * DMODEL;     // 8,388,608
constexpr int NW     = DMODEL * DMODEL; // 1,048,576

__device__ __forceinline__ u16 f2bf(float f) {
  union { float f; unsigned u; } v; v.f = f;
  unsigned r = v.u + 0x7fffu + ((v.u >> 16) & 1u);
  return (u16)(r >> 16);
}
__device__ __forceinline__ float bf2f(u16 h) {
  union { unsigned u; float f; } v; v.u = ((unsigned)h) << 16;
  return v.f;
}
__device__ __forceinline__ unsigned fbits(float f) { union { float f; unsigned u; } v; v.f = f; return v.u; }
__device__ __forceinline__ float bitsf(unsigned u) { union { unsigned u; float f; } v; v.u = u; return v.f; }
// packed f32x2 -> bf16x2 via v_cvt_pk_bf16_f32
__device__ __forceinline__ unsigned pk2(float a, float b) {
  float2 t; t.x = a; t.y = b;
  __hip_bfloat162 h = __float22bfloat162_rn(t);
  return *reinterpret_cast<unsigned*>(&h);
}
// lane[l] <-> lane[l^32] exchange machinery (gfx950 permlane32_swap)
__device__ __forceinline__ u32x2 plswap(unsigned a, unsigned b) {
  return __builtin_amdgcn_permlane32_swap(a, b, false, false);
}
__device__ __forceinline__ f32x16 mfma32(s16x8 a, s16x8 b, f32x16 c) {
  return __builtin_amdgcn_mfma_f32_32x32x16_bf16(a, b, c, 0, 0, 0);
}
__device__ __forceinline__ void gload_lds16(const void* g, void* l) {
  __builtin_amdgcn_global_load_lds(
      (const __attribute__((address_space(1))) void*)g,
      (__attribute__((address_space(3))) void*)l, 16, 0, 0);
}

// ---------------- fp32 -> bf16 conversion for x and W[qkvo] ----------------
__global__ __launch_bounds__(256) void convert_all(
    const float* __restrict__ x, const float* __restrict__ wq,
    const float* __restrict__ wk, const float* __restrict__ wv,
    const float* __restrict__ wo, u16* __restrict__ xb, u16* __restrict__ Wb) {
  int t = blockIdx.x * 256 + threadIdx.x;
  int i = t * 4;
  const float* src; u16* dst;
  if (i < NX) { src = x + i; dst = xb + i; }
  else {
    int j = i - NX; int w = j >> 20; int jj = j & (NW - 1);
    src = (w == 0 ? wq : w == 1 ? wk : w == 2 ? wv : wo) + jj;
    dst = Wb + j;
  }
  float4 v = *reinterpret_cast<const float4*>(src);
  uint2 pk; pk.x = pk2(v.x, v.y); pk.y = pk2(v.z, v.w);
  *reinterpret_cast<uint2*>(dst) = pk;
}

// ---------------- 128x128 bf16 GEMM, C = A * B^T (B rows = output cols) ----
template <int EPI>
__global__ __launch_bounds__(256) void gemm128(
    const u16* __restrict__ A, const u16* __restrict__ B,
    u16* __restrict__ Qw, u16* __restrict__ Kw, u16* __restrict__ Vt,
    float* __restrict__ Co) {
  __shared__ u16 lA[128 * 32];
  __shared__ u16 lB[128 * 32];
  const int tid = threadIdx.x, w = tid >> 6, l = tid & 63;
  const int wr = w >> 1, wc = w & 1;
  const int m0 = blockIdx.y * 128, n0 = blockIdx.x * 128;
  constexpr int K = 1024;
  f32x4 acc[4][4] = {};
  const int li = l & 15, lg = l >> 4;
  const int srow = l >> 2, skc = (l & 3) * 8;
  for (int k0 = 0; k0 < K; k0 += 32) {
    __syncthreads();
#pragma unroll
    for (int cc = 0; cc < 2; ++cc) {
      const int c = 2 * w + cc;
      const int row = c * 16 + srow;
      gload_lds16(A + (size_t)(m0 + row) * K + k0 + skc, &lA[c * 512]);
      gload_lds16(B + (size_t)(n0 + row) * K + k0 + skc, &lB[c * 512]);
    }
    __syncthreads();
    s16x8 af[4], bfr[4];
#pragma unroll
    for (int i = 0; i < 4; ++i)
      af[i] = *reinterpret_cast<const s16x8*>(&lA[(wr * 64 + i * 16 + li) * 32 + lg * 8]);
#pragma unroll
    for (int j = 0; j < 4; ++j)
      bfr[j] = *reinterpret_cast<const s16x8*>(&lB[(wc * 64 + j * 16 + li) * 32 + lg * 8]);
#pragma unroll
    for (int i = 0; i < 4; ++i)
#pragma unroll
      for (int j = 0; j < 4; ++j)
        acc[i][j] = __builtin_amdgcn_mfma_f32_16x16x32_bf16(af[i], bfr[j], acc[i][j], 0, 0, 0);
  }
#pragma unroll
  for (int i = 0; i < 4; ++i) {
    const int mbase = m0 + wr * 64 + i * 16 + lg * 4;
#pragma unroll
    for (int j = 0; j < 4; ++j) {
      const int n = n0 + wc * 64 + j * 16 + li;
      if (EPI == 0) {
        const int which = n >> 10, nn = n & 1023, h = nn >> 6, d = nn & 63;
#pragma unroll
        for (int r = 0; r < 4; ++r) {
          const int m = mbase + r, b = m >> 12, s = m & (SEQ - 1);
          const int bh = b * NH + h;
          const u16 val = f2bf(acc[i][j][r]);
          if (which == 0)      Qw[((size_t)bh * SEQ + s) * DK + d] = val;
          else if (which == 1) Kw[((size_t)bh * SEQ + s) * DK + d] = val;
          else                 Vt[((size_t)bh * DK + d) * SEQ + s] = val;
        }
      } else {
#pragma unroll
        for (int r = 0; r < 4; ++r)
          Co[(size_t)(mbase + r) * DMODEL + n] = acc[i][j][r];
      }
    }
  }
}

// -------- RoPE in-place; Q additionally scaled by (1/8)*log2(e) for exp2 ---
__global__ __launch_bounds__(256) void rope_qk(u16* __restrict__ Qw, u16* __restrict__ Kw,
                                               const int* __restrict__ pos) {
  const int TOT = BATCH * NH * SEQ * 32;  // pairs per tensor
  int t = blockIdx.x * 256 + threadIdx.x;
  const bool isQ = (t < TOT);
  u16* arr = isQ ? Qw : Kw;
  int p = isQ ? t : t - TOT;
  const int i = p & 31;
  const int s = (p >> 5) & (SEQ - 1);
  const int bh = p >> 17;
  const float inv = expf(-(float)i * 0.28782313662425574f);
  const float ang = (float)pos[s] * inv;
  float sn, cs;
  sincosf(ang, &sn, &cs);
  const float sc = isQ ? 0.18033688011112042f : 1.0f;  // 0.125 * log2(e)
  u16* ptr = arr + ((size_t)bh * SEQ + s) * DK + 2 * i;
  unsigned v = *reinterpret_cast<unsigned*>(ptr);
  float xe = bf2f((u16)(v & 0xffffu)), xo = bf2f((u16)(v >> 16));
  float oe = (xe * cs - xo * sn) * sc;
  float oo = (xe * sn + xo * cs) * sc;
  *reinterpret_cast<unsigned*>(ptr) = pk2(oe, oo);
}

// ---------------- causal flash attention, 32x32 MFMA, no P-LDS -------------
// 512 uniform paired blocks (tiles 31-j and j), 4 waves x 32 q-rows,
// KBLK=128 staged (two 64k compute sub-phases per staging iteration).
// Swapped MFMAs: sc=mfma(K,Q) -> q = lane&31 lane-local. Softmax reduces and
// the score->PV-fragment relayout use v_permlane32_swap (lane l <-> l^32);
// P never touches LDS.
__global__ __launch_bounds__(256, 2) void attn_kernel(
    const u16* __restrict__ Qw, const u16* __restrict__ Kw,
    const u16* __restrict__ Vt, u16* __restrict__ Ob) {
  __shared__ __align__(16) u16 Kb[2][8192];  // [128 k][64 d], rows 128B, XOR-swizzled
  __shared__ __align__(16) u16 Vb[2][8192];  // [64 d][128 k], rows 256B, XOR-swizzled
  const int tid = threadIdx.x, w = tid >> 6, l = tid & 63;
  const int lq = l & 31, hi = l >> 5;
  const int id = blockIdx.x;
  const int g = (id & 7) * 64 + (id >> 3);    // XCD-chunked (64 blocks/XCD)
  const int bh = g >> 4;                      // 4 heads per XCD chunk
  const int j  = g & 15;                      // pair index
  const int tA = 31 - j, tB = j;              // heavy first
  const int nA = 32 - j;                      // 128k-iters in phase A
  const int ntot = 33;                        // + (j+1) in phase B
  const u16* Qh = Qw + (size_t)bh * SEQ * DK;
  const u16* Kh = Kw + (size_t)bh * SEQ * DK;
  const u16* Vh = Vt + (size_t)bh * DK * SEQ;
  const int b = bh >> 4, h = bh & 15;

  s16x8 aq[4];
  f32x16 o0, o1;
  float mrun, lrun;

  auto loadQ = [&](int q0) {
#pragma unroll
    for (int ds = 0; ds < 4; ++ds)
      aq[ds] = *reinterpret_cast<const s16x8*>(
          &Qh[(size_t)(q0 + lq) * DK + ds * 16 + hi * 8]);
  };
  auto resetState = [&]() {
    mrun = -1e30f; lrun = 0.f;
    o0 = f32x16{}; o1 = f32x16{};
  };
  auto writeO = [&](int q0) {
    const float inv = 1.f / lrun;
    u16* orow = Ob + ((size_t)(b * SEQ + q0 + lq)) * DMODEL + h * DK;
#pragma unroll
    for (int m = 0; m < 4; ++m) {
      uint2 pa;
      pa.x = pk2(o0[4 * m + 0] * inv, o0[4 * m + 1] * inv);
      pa.y = pk2(o0[4 * m + 2] * inv, o0[4 * m + 3] * inv);
      *reinterpret_cast<uint2*>(orow + 8 * m + 4 * hi) = pa;
      uint2 pb;
      pb.x = pk2(o1[4 * m + 0] * inv, o1[4 * m + 1] * inv);
      pb.y = pk2(o1[4 * m + 2] * inv, o1[4 * m + 3] * inv);
      *reinterpret_cast<uint2*>(orow + 32 + 8 * m + 4 * hi) = pb;
    }
  };
  auto stage = [&](int buf, int kt) {
    const int krow = tid >> 3;                                  // 0..31
    const int kcol = ((tid & 7) * 16) ^ ((krow & 7) << 4);
#pragma unroll
    for (int i = 0; i < 4; ++i)
      gload_lds16((const char*)Kh + (size_t)(kt + i * 32 + krow) * 128 + kcol,
                  (char*)&Kb[buf][0] + i * 4096 + tid * 16);
    const int vrow = tid >> 4;                                  // 0..15
    const int vcol = ((tid & 15) * 16) ^ ((vrow & 7) << 4);
#pragma unroll
    for (int i = 0; i < 4; ++i)
      gload_lds16((const char*)Vh + (size_t)(i * 16 + vrow) * (SEQ * 2) + kt * 2 + vcol,
                  (char*)&Vb[buf][0] + i * 4096 + tid * 16);
  };

  int q0 = tA * 128 + w * 32;
  loadQ(q0);
  resetState();
  stage(0, 0);
  int kt = 0;
  for (int it = 0; it < ntot; ++it) {
    asm volatile("s_waitcnt vmcnt(0)" ::: "memory");  // current buf staged
    __builtin_amdgcn_s_barrier();
    __builtin_amdgcn_sched_barrier(0);
    const int itn = it + 1;
    const int ktn = (itn < nA) ? 128 * itn : (itn < ntot ? 128 * (itn - nA) : 0);
    stage(itn & 1, ktn);
    const int cur = it & 1;
#pragma unroll
    for (int sub = 0; sub < 2; ++sub) {
      const int ksub = kt + sub * 64;
      if (ksub > q0 + 31) continue;  // fully masked for this wave
      // ---- QK^T (swapped): rows k, col q = lane&31
      f32x16 s0 = {}, s1 = {};
      const char* kb = (const char*)&Kb[cur][0] + (sub * 64 + lq) * 128;
      __builtin_amdgcn_s_setprio(1);
#pragma unroll
      for (int ds = 0; ds < 4; ++ds) {
        const int co = (ds * 32 + hi * 16) ^ ((lq & 7) << 4);
        s16x8 k0 = *reinterpret_cast<const s16x8*>(kb + co);
        s16x8 k1 = *reinterpret_cast<const s16x8*>(kb + 32 * 128 + co);
        s0 = mfma32(k0, aq[ds], s0);
        s1 = mfma32(k1, aq[ds], s1);
      }
      __builtin_amdgcn_s_setprio(0);
      if (ksub + 63 > q0) {  // causal mask on the diagonal sub-phase
#pragma unroll
        for (int r = 0; r < 16; ++r) {
          const int kr = (r & 3) + 8 * (r >> 2) + 4 * hi;
          if (ksub + kr > q0 + lq) s0[r] = -1e30f;
          if (ksub + 32 + kr > q0 + lq) s1[r] = -1e30f;
        }
      }
      // ---- online softmax (log2 domain), q lane-local
      float mx = s0[0];
#pragma unroll
      for (int r = 1; r < 16; ++r) mx = fmaxf(mx, s0[r]);
#pragma unroll
      for (int r = 0; r < 16; ++r) mx = fmaxf(mx, s1[r]);
      {
        u32x2 pr = plswap(fbits(mx), fbits(mx));
        mx = fmaxf(bitsf(pr.x), bitsf(pr.y));
      }
      if (!__all(mx <= mrun + 8.f)) {  // defer-max: rescale is rare
        const float mn = fmaxf(mrun, mx);
        const float fs = exp2f(mrun - mn);
        mrun = mn; lrun *= fs;
        o0 *= fs; o1 *= fs;
      }
      float rs = 0.f;
#pragma unroll
      for (int r = 0; r < 16; ++r) { s0[r] = exp2f(s0[r] - mrun); rs += s0[r]; }
#pragma unroll
      for (int r = 0; r < 16; ++r) { s1[r] = exp2f(s1[r] - mrun); rs += s1[r]; }
      {
        u32x2 pr = plswap(fbits(rs), fbits(rs));
        rs = bitsf(pr.x) + bitsf(pr.y);
      }
      lrun += rs;
      // ---- pack P to bf16 pairs; in-register relayout to PV B-fragments
      unsigned U0[8], U1[8];  // [m*2+p]: k rows 8m+4hi+{2p,2p+1}
#pragma unroll
      for (int m = 0; m < 4; ++m) {
        U0[m * 2 + 0] = pk2(s0[4 * m + 0], s0[4 * m + 1]);
        U0[m * 2 + 1] = pk2(s0[4 * m + 2], s0[4 * m + 3]);
        U1[m * 2 + 0] = pk2(s1[4 * m + 0], s1[4 * m + 1]);
        U1[m * 2 + 1] = pk2(s1[4 * m + 2], s1[4 * m + 3]);
      }
      // ---- PV (swapped): o rows d, col q; accumulate over 4 k16-chunks
      const char* vb = (const char*)&Vb[cur][0];
#pragma unroll
      for (int c16 = 0; c16 < 4; ++c16) {
        unsigned* U = (c16 < 2) ? U0 : U1;
        const int m0i = (c16 & 1) * 2, m1i = m0i + 1;
        u32x2 r0 = plswap(U[m0i * 2 + 0], U[m1i * 2 + 0]);
        u32x2 r1 = plswap(U[m0i * 2 + 1], U[m1i * 2 + 1]);
        union { uint4 u; s16x8 s; } cf;
        cf.u.x = r0.x; cf.u.y = r1.x; cf.u.z = r0.y; cf.u.w = r1.y;
        const int co = (sub * 128 + c16 * 32 + hi * 16) ^ ((lq & 7) << 4);
        s16x8 v0 = *reinterpret_cast<const s16x8*>(vb + lq * 256 + co);
        s16x8 v1 = *reinterpret_cast<const s16x8*>(vb + (32 + lq) * 256 + co);
        __builtin_amdgcn_s_setprio(1);
        o0 = mfma32(v0, cf.s, o0);
        o1 = mfma32(v1, cf.s, o1);
        __builtin_amdgcn_s_setprio(0);
      }
    }
    if (it == nA - 1) {  // phase switch: flush tile A, start tile B
      writeO(q0);
      q0 = tB * 128 + w * 32;
      loadQ(q0);
      resetState();
    }
    kt = ktn;
  }
  writeO(q0);
}

extern "C" void kernel_launch(void* const* d_in, const int* in_sizes, int n_in,
                              void* d_out, int out_size, void* d_ws, size_t ws_size,
                              hipStream_t stream) {
  const float* x  = (const float*)d_in[0];
  const int*  pos = (const int*)d_in[1];
  const float* wq = (const float*)d_in[2];
  const float* wk = (const float*)d_in[3];
  const float* wv = (const float*)d_in[4];
  const float* wo = (const float*)d_in[5];
  float* out = (float*)d_out;

  u16* Wb = (u16*)d_ws;               // 4*NW bf16 (Wq|Wk|Wv|Wo)
  u16* xb = Wb + 4 * (size_t)NW;      // NX bf16
  u16* Qw = xb + (size_t)NX;          // (b,h,s,d)
  u16* Kw = Qw + (size_t)NX;          // (b,h,s,d)
  u16* Vt = Kw + (size_t)NX;          // (b,h,d,s)
  u16* Ab = xb;                       // reuse x-bf16 region for attn output

  convert_all<<<(NX + 4 * NW) / 4 / 256, 256, 0, stream>>>(x, wq, wk, wv, wo, xb, Wb);
  gemm128<0><<<dim3(24, 64), 256, 0, stream>>>(xb, Wb, Qw, Kw, Vt, nullptr);
  rope_qk<<<2 * (BATCH * NH * SEQ * 32) / 256, 256, 0, stream>>>(Qw, Kw, pos);
  attn_kernel<<<512, 256, 0, stream>>>(Qw, Kw, Vt, Ab);
  gemm128<1><<<dim3(8, 64), 256, 0, stream>>>(Ab, Wb + 3 * (size_t)NW, nullptr, nullptr, nullptr, out);
}